// Round 6
// baseline (751.539 us; speedup 1.0000x reference)
//
#include <hip/hip_runtime.h>
#include <hip/hip_bf16.h>
#include <cstdint>
#include <cstddef>

#define N_SPATIAL_C 65160
#define N_SPHERE_C  2883
#define N_EDGES_C   131072

typedef short bf16x8 __attribute__((ext_vector_type(8)));
typedef float f32x4  __attribute__((ext_vector_type(4)));

__device__ inline float bf2f(ushort u) {
    union { uint u; float f; } c; c.u = ((uint)u) << 16; return c.f;
}
__device__ inline ushort f2bf(float f) {
    __hip_bfloat16 h = __float2bfloat16(f);
    union { __hip_bfloat16 h; ushort u; } c; c.h = h; return c.u;
}

// ---------------------------------------------------------------------------
// Direct-global swapped-operand MFMA GEMM.
// C(M x 256) = A(M x KI bf16, row stride lda) @ Bt(256 x KI bf16 = B^T)
// Block: 4 waves, tile 64 rows x 256 cols; wave w owns cols [w*64, w*64+64).
// Operands SWAPPED in the MFMA (a_frag <- Bt row, b_frag <- A row), so
// D[col][edge]: acc[rt][ct][reg] = C[m0+rt*16+lo][bn+ct*16+hi*4+reg].
// => each lane holds one output ROW (per rt) as 4x f32x4 chunks: LN, P/R
// gathers, bias and stores are all register-resident row-major vector ops.
// No LDS operand staging; A rows stream from HBM (full 512B row touched by
// the unrolled K-loop), Bt (128KB) is L2-resident, reused by all blocks.
// EPI: 0 = +bias store; 1 = +bias [+cnt*bx] relu LN; 2 = +bias+P[s]+R[r] relu LN.
// EPI==2 runs in place (C==A): each block reads only its own 64 rows; the
// LN-reduce __syncthreads() orders all A reads before any C write.
// ---------------------------------------------------------------------------
template<int EPI, int KI, typename OutT>
__global__ __launch_bounds__(256, 3) void mfma_gemm(
    const ushort* __restrict__ A, const ushort* __restrict__ Bt,
    OutT* __restrict__ C, int M, int lda, int ldc,
    const float* __restrict__ bias,
    const float* __restrict__ g, const float* __restrict__ o,
    const ushort* __restrict__ P, const int* __restrict__ senders,
    const float* __restrict__ Rf, const int* __restrict__ receivers,
    const int* __restrict__ cntv, const float* __restrict__ bxv)
{
    __shared__ float red1[4][64];
    __shared__ float red2[4][64];

    const int m0   = blockIdx.x * 64;
    const int t    = threadIdx.x;
    const int w    = t >> 6;
    const int lane = t & 63;
    const int lo   = lane & 15, hi = lane >> 4;
    const int bn   = w * 64;

    f32x4 acc[4][4];
#pragma unroll
    for (int rt = 0; rt < 4; ++rt)
#pragma unroll
        for (int ct = 0; ct < 4; ++ct)
#pragma unroll
            for (int j = 0; j < 4; ++j) acc[rt][ct][j] = 0.f;

    int arow[4];
#pragma unroll
    for (int rt = 0; rt < 4; ++rt) {
        int r = m0 + rt * 16 + lo;
        arow[rt] = (r < M) ? r : (M - 1);
    }

    // ---- K loop: direct global loads, fully unrolled ----
#pragma unroll
    for (int ks = 0; ks < KI / 32; ++ks) {
        bf16x8 bt[4], ar[4];
#pragma unroll
        for (int ct = 0; ct < 4; ++ct)
            bt[ct] = *reinterpret_cast<const bf16x8*>(
                Bt + (size_t)(bn + ct * 16 + lo) * KI + ks * 32 + hi * 8);
#pragma unroll
        for (int rt = 0; rt < 4; ++rt)
            ar[rt] = *reinterpret_cast<const bf16x8*>(
                A + (size_t)arow[rt] * lda + ks * 32 + hi * 8);
#pragma unroll
        for (int rt = 0; rt < 4; ++rt)
#pragma unroll
            for (int ct = 0; ct < 4; ++ct)
                acc[rt][ct] = __builtin_amdgcn_mfma_f32_16x16x32_bf16(
                    bt[ct], ar[rt], acc[rt][ct], 0, 0, 0);
    }

    // ---- epilogue: fully register-resident, row-major per lane ----
    // acc[rt][ct][reg] = C[m0+rt*16+lo][bn+ct*16+hi*4+reg]
    const int c00 = bn + hi * 4;

#pragma unroll
    for (int rt = 0; rt < 4; ++rt) {
        int e  = m0 + rt * 16 + lo;
        int ec = (e < M) ? e : (M - 1);

        if (bias) {
#pragma unroll
            for (int ct = 0; ct < 4; ++ct) {
                f32x4 v = *reinterpret_cast<const f32x4*>(bias + c00 + ct * 16);
#pragma unroll
                for (int j = 0; j < 4; ++j) acc[rt][ct][j] += v[j];
            }
        }
        if (EPI == 1 && cntv) {
            float cf = (float)cntv[ec];
#pragma unroll
            for (int ct = 0; ct < 4; ++ct) {
                f32x4 v = *reinterpret_cast<const f32x4*>(bxv + c00 + ct * 16);
#pragma unroll
                for (int j = 0; j < 4; ++j) acc[rt][ct][j] += cf * v[j];
            }
        }
        if (EPI == 2) {
            int sIdx = senders[ec];
            int rIdx = receivers[ec] - N_SPATIAL_C;
#pragma unroll
            for (int ct = 0; ct < 4; ++ct) {
                ushort4 pv = *reinterpret_cast<const ushort4*>(
                    P + (size_t)sIdx * 256 + c00 + ct * 16);
                f32x4 rv = *reinterpret_cast<const f32x4*>(
                    Rf + (size_t)rIdx * 256 + c00 + ct * 16);
                acc[rt][ct][0] += bf2f(pv.x) + rv[0];
                acc[rt][ct][1] += bf2f(pv.y) + rv[1];
                acc[rt][ct][2] += bf2f(pv.z) + rv[2];
                acc[rt][ct][3] += bf2f(pv.w) + rv[3];
            }
        }
        if (EPI >= 1) {
#pragma unroll
            for (int ct = 0; ct < 4; ++ct)
#pragma unroll
                for (int j = 0; j < 4; ++j)
                    acc[rt][ct][j] = fmaxf(acc[rt][ct][j], 0.f);
        }
    }

    if (EPI >= 1) {
        float s1v[4], s2v[4];
#pragma unroll
        for (int rt = 0; rt < 4; ++rt) {
            float s1 = 0.f, s2 = 0.f;
#pragma unroll
            for (int ct = 0; ct < 4; ++ct)
#pragma unroll
                for (int j = 0; j < 4; ++j) {
                    float y = acc[rt][ct][j];
                    s1 += y; s2 += y * y;
                }
            s1 += __shfl_xor(s1, 16); s2 += __shfl_xor(s2, 16);
            s1 += __shfl_xor(s1, 32); s2 += __shfl_xor(s2, 32);
            s1v[rt] = s1; s2v[rt] = s2;
        }
        if (hi == 0) {
#pragma unroll
            for (int rt = 0; rt < 4; ++rt) {
                red1[w][rt * 16 + lo] = s1v[rt];
                red2[w][rt * 16 + lo] = s2v[rt];
            }
        }
        __syncthreads();   // also orders in-place A reads before C writes

#pragma unroll
        for (int rt = 0; rt < 4; ++rt) {
            int el = rt * 16 + lo;
            float t1 = red1[0][el] + red1[1][el] + red1[2][el] + red1[3][el];
            float t2 = red2[0][el] + red2[1][el] + red2[2][el] + red2[3][el];
            float mean = t1 * (1.f / 256.f);
            float var  = t2 * (1.f / 256.f) - mean * mean;
            float rstd = rsqrtf(var + 1e-5f);
#pragma unroll
            for (int ct = 0; ct < 4; ++ct) {
                f32x4 gv = *reinterpret_cast<const f32x4*>(g + c00 + ct * 16);
                f32x4 ov = *reinterpret_cast<const f32x4*>(o + c00 + ct * 16);
#pragma unroll
                for (int j = 0; j < 4; ++j)
                    acc[rt][ct][j] = (acc[rt][ct][j] - mean) * rstd * gv[j] + ov[j];
            }
        }
    }

    // ---- stores ----
#pragma unroll
    for (int rt = 0; rt < 4; ++rt) {
        int e = m0 + rt * 16 + lo;
        if (e < M) {
            if constexpr (sizeof(OutT) == 2) {
#pragma unroll
                for (int ct = 0; ct < 4; ++ct) {
                    ushort4 u;
                    u.x = f2bf(acc[rt][ct][0]); u.y = f2bf(acc[rt][ct][1]);
                    u.z = f2bf(acc[rt][ct][2]); u.w = f2bf(acc[rt][ct][3]);
                    *reinterpret_cast<ushort4*>(
                        (ushort*)C + (size_t)e * ldc + c00 + ct * 16) = u;
                }
            } else {
#pragma unroll
                for (int ct = 0; ct < 4; ++ct)
                    *reinterpret_cast<f32x4*>(
                        (float*)C + (size_t)e * ldc + c00 + ct * 16) = acc[rt][ct];
            }
        }
    }
}

// ---------------------------------------------------------------------------
// Step-0 edge fuse: H = LN(relu(edges3@Ae + P0[s] + R[rid] + be1)) * g + o
// ---------------------------------------------------------------------------
__global__ __launch_bounds__(256) void fuse0(
    const float* __restrict__ edges3, const float* __restrict__ Ae,
    const ushort* __restrict__ P, const int* __restrict__ senders,
    const float* __restrict__ Rf, const int* __restrict__ receivers,
    const float* __restrict__ be1, const float* __restrict__ g,
    const float* __restrict__ o, ushort* __restrict__ H)
{
    int row  = blockIdx.x * 4 + (threadIdx.x >> 6);
    int lane = threadIdx.x & 63;
    int c = lane * 4;

    float e0 = edges3[(size_t)row * 3 + 0];
    float e1 = edges3[(size_t)row * 3 + 1];
    float e2 = edges3[(size_t)row * 3 + 2];
    int s = senders[row];
    int r = receivers[row] - N_SPATIAL_C;
    ushort4 pv = *reinterpret_cast<const ushort4*>(P + (size_t)s * 256 + c);
    float4  rv = *reinterpret_cast<const float4*>(Rf + (size_t)r * 256 + c);

    float pw[4] = {bf2f(pv.x), bf2f(pv.y), bf2f(pv.z), bf2f(pv.w)};
    float rw[4] = {rv.x, rv.y, rv.z, rv.w};
    float x[4];
#pragma unroll
    for (int j = 0; j < 4; ++j) {
        x[j] = e0 * Ae[c + j] + e1 * Ae[256 + c + j] + e2 * Ae[512 + c + j]
             + be1[c + j] + pw[j] + rw[j];
        x[j] = fmaxf(x[j], 0.f);
    }
    float s1 = x[0] + x[1] + x[2] + x[3];
    float s2 = x[0]*x[0] + x[1]*x[1] + x[2]*x[2] + x[3]*x[3];
#pragma unroll
    for (int m = 32; m > 0; m >>= 1) { s1 += __shfl_xor(s1, m); s2 += __shfl_xor(s2, m); }
    float mean = s1 * (1.f / 256.f);
    float var  = s2 * (1.f / 256.f) - mean * mean;
    float rstd = rsqrtf(var + 1e-5f);
#pragma unroll
    for (int j = 0; j < 4; ++j) {
        float y = (x[j] - mean) * rstd * g[c + j] + o[c + j];
        H[(size_t)row * 256 + c + j] = f2bf(y);
    }
}

// ---------------------------------------------------------------------------
// CSR build (receivers fixed across all steps)
// ---------------------------------------------------------------------------
__global__ void count_k(const int* __restrict__ receivers, int* __restrict__ cnt)
{
    int e = blockIdx.x * 256 + threadIdx.x;
    if (e < N_EDGES_C) atomicAdd(&cnt[receivers[e] - N_SPATIAL_C], 1);
}

__global__ void scan_k(const int* __restrict__ cnt, int* __restrict__ row_start)
{
    __shared__ int sums[257];
    const int CH = 12;
    int t = threadIdx.x;
    int local = 0;
    for (int i = 0; i < CH; ++i) {
        int idx = t * CH + i;
        if (idx < N_SPHERE_C) local += cnt[idx];
    }
    sums[t] = local;
    __syncthreads();
    if (t == 0) {
        int run = 0;
        for (int i = 0; i < 256; ++i) { int v = sums[i]; sums[i] = run; run += v; }
        sums[256] = run;
    }
    __syncthreads();
    int base = sums[t];
    for (int i = 0; i < CH; ++i) {
        int idx = t * CH + i;
        if (idx < N_SPHERE_C) { row_start[idx] = base; base += cnt[idx]; }
    }
    if (t == 0) row_start[N_SPHERE_C] = sums[256];
}

__global__ void fill_k(const int* __restrict__ receivers, const int* __restrict__ row_start,
                       int* __restrict__ cursor, int* __restrict__ csr)
{
    int e = blockIdx.x * 256 + threadIdx.x;
    if (e < N_EDGES_C) {
        int rid = receivers[e] - N_SPATIAL_C;
        int pos = atomicAdd(&cursor[rid], 1);
        csr[row_start[rid] + pos] = e;
    }
}

// S[n][d] = bf16( sum_{e in seg(n)} H[e][d] ), output row stride ldS
__global__ __launch_bounds__(256) void seg_gather(
    const ushort* __restrict__ H, const int* __restrict__ row_start,
    const int* __restrict__ csr, ushort* __restrict__ S, int ldS)
{
    __shared__ float red[3][64][4];
    int n = blockIdx.x;
    int sub = threadIdx.x >> 6, l = threadIdx.x & 63, c = l * 4;
    int beg = row_start[n], end = row_start[n + 1];
    float a0 = 0.f, a1 = 0.f, a2 = 0.f, a3 = 0.f;
    for (int i = beg + sub; i < end; i += 4) {
        int e = csr[i];
        ushort4 v = *reinterpret_cast<const ushort4*>(H + (size_t)e * 256 + c);
        a0 += bf2f(v.x); a1 += bf2f(v.y); a2 += bf2f(v.z); a3 += bf2f(v.w);
    }
    if (sub) { red[sub-1][l][0]=a0; red[sub-1][l][1]=a1; red[sub-1][l][2]=a2; red[sub-1][l][3]=a3; }
    __syncthreads();
    if (sub == 0) {
#pragma unroll
        for (int s_ = 0; s_ < 3; ++s_) {
            a0 += red[s_][l][0]; a1 += red[s_][l][1];
            a2 += red[s_][l][2]; a3 += red[s_][l][3];
        }
        ushort4 u; u.x = f2bf(a0); u.y = f2bf(a1); u.z = f2bf(a2); u.w = f2bf(a3);
        *reinterpret_cast<ushort4*>(S + (size_t)n * ldS + c) = u;
    }
}

// Wt[j][koff+k] = bf16( (We2 @ Bsrc)[k][j] ), dst row stride ldd
__global__ __launch_bounds__(256) void wprod_kernel(
    const float* __restrict__ We2, const float* __restrict__ Bsrc,
    ushort* __restrict__ Wt, int ldd, int koff)
{
    __shared__ float colB[256];
    int j = blockIdx.x, k = threadIdx.x;
    colB[k] = Bsrc[(size_t)k * 256 + j];
    __syncthreads();
    const float* wrow = We2 + (size_t)k * 256;
    float acc = 0.f;
    for (int t = 0; t < 256; ++t) acc += wrow[t] * colB[t];
    Wt[(size_t)j * ldd + koff + k] = f2bf(acc);
}

// bout[j] = base[j]? + sum_k bvec[k] * W[k][j]
__global__ void bvecprod_kernel(const float* __restrict__ base, const float* __restrict__ bvec,
                                const float* __restrict__ W, float* __restrict__ bout)
{
    int j = threadIdx.x;
    float acc = base ? base[j] : 0.f;
    for (int k = 0; k < 256; ++k) acc += bvec[k] * W[(size_t)k * 256 + j];
    bout[j] = acc;
}

// Wt[n*ldd + k] = bf16(W[k][n]);  W: Ksrc x 256 row-major, grid (Ksrc/16, 16)
__global__ void tcast2(const float* __restrict__ W, ushort* __restrict__ Wt, int ldd)
{
    __shared__ float tbuf[16][17];
    int k0 = blockIdx.x * 16, n0 = blockIdx.y * 16;
    int tx = threadIdx.x, ty = threadIdx.y;
    tbuf[ty][tx] = W[(size_t)(k0 + ty) * 256 + n0 + tx];
    __syncthreads();
    Wt[(size_t)(n0 + ty) * ldd + k0 + tx] = f2bf(tbuf[tx][ty]);
}

__global__ void cast_f32_bf16(const float* __restrict__ src, ushort* __restrict__ dst, int n4)
{
    int i = blockIdx.x * 256 + threadIdx.x;
    if (i < n4) {
        float4 v = *reinterpret_cast<const float4*>(src + (size_t)i * 4);
        ushort4 u;
        u.x = f2bf(v.x); u.y = f2bf(v.y); u.z = f2bf(v.z); u.w = f2bf(v.w);
        *reinterpret_cast<ushort4*>(dst + (size_t)i * 4) = u;
    }
}

// sphere rows of nodes (fp32) -> node_in left half (bf16, stride 512)
__global__ void cast_sphere(const float* __restrict__ nodes, ushort* __restrict__ node_in)
{
    int n = blockIdx.x, d = threadIdx.x;
    node_in[(size_t)n * 512 + d] =
        f2bf(nodes[(size_t)(N_SPATIAL_C + n) * 256 + d]);
}

// ---------------------------------------------------------------------------
extern "C" void kernel_launch(void* const* d_in, const int* in_sizes, int n_in,
                              void* d_out, int out_size, void* d_ws, size_t ws_size,
                              hipStream_t stream)
{
    const float* nodes     = (const float*)d_in[0];
    const float* edges3    = (const float*)d_in[1];
    const int*   senders   = (const int*)d_in[2];
    const int*   receivers = (const int*)d_in[3];
    const float* We1a      = (const float*)d_in[4];
    const float* We1b      = (const float*)d_in[5];
    const float* be1       = (const float*)d_in[6];
    const float* ge        = (const float*)d_in[7];
    const float* oe        = (const float*)d_in[8];
    const float* We2       = (const float*)d_in[9];
    const float* be2       = (const float*)d_in[10];
    const float* Wn1       = (const float*)d_in[11];
    const float* bn1       = (const float*)d_in[12];
    const float* gn        = (const float*)d_in[13];
    const float* on_       = (const float*)d_in[14];
    const float* Wn2       = (const float*)d_in[15];
    const float* bn2       = (const float*)d_in[16];

    const float* Ae  = We1a;               // rows 0..2
    const float* As_ = We1a + 3 * 256;     // sender part, step 0
    const float* Ar  = We1a + 259 * 256;   // receiver part, step 0
    const float* Be  = We1b;               // edge part, steps 1,2
    const float* Bs_ = We1b + 256 * 256;   // sender part, steps 1,2
    const float* Br  = We1b + 512 * 256;   // receiver part, steps 1,2
    const float* Wn1bot = Wn1 + 256 * 256; // message part of Wn1

    char* ws = (char*)d_ws;
    size_t off = 0;
    auto alloc = [&](size_t b) -> char* {
        char* p = ws + off;
        off += (b + 255) & ~(size_t)255;
        return p;
    };
    ushort* H          = (ushort*)alloc((size_t)N_EDGES_C * 256 * 2);    // 67 MB
    ushort* Pb         = (ushort*)alloc((size_t)N_SPATIAL_C * 256 * 2);  // 33 MB
    ushort* nodes_bf   = (ushort*)alloc((size_t)N_SPATIAL_C * 256 * 2);  // 33 MB
    float*  Rf         = (float*)alloc((size_t)N_SPHERE_C * 256 * 4);
    ushort* node_in_bf = (ushort*)alloc((size_t)N_SPHERE_C * 512 * 2);   // [sphere|S]
    ushort* nH         = (ushort*)alloc((size_t)N_SPHERE_C * 256 * 2);
    ushort* Ast  = (ushort*)alloc(256 * 256 * 2);
    ushort* Art  = (ushort*)alloc(256 * 256 * 2);
    ushort* Bst  = (ushort*)alloc(256 * 256 * 2);
    ushort* Brt  = (ushort*)alloc(256 * 256 * 2);
    ushort* Wn2t = (ushort*)alloc(256 * 256 * 2);
    ushort* Wft  = (ushort*)alloc(256 * 256 * 2);
    ushort* Bnt  = (ushort*)alloc(256 * 512 * 2);   // [Wn1_top ; We2@Wn1_bot]^T
    float*  bfc  = (float*)alloc(256 * 4);
    float*  bxv  = (float*)alloc(256 * 4);
    int* cnt       = (int*)alloc(N_SPHERE_C * 4);
    int* cursor    = (int*)alloc(N_SPHERE_C * 4);
    int* row_start = (int*)alloc((N_SPHERE_C + 1) * 4);
    int* csr       = (int*)alloc((size_t)N_EDGES_C * 4);

    // CSR build
    hipMemsetAsync(cnt, 0, N_SPHERE_C * 4, stream);
    hipMemsetAsync(cursor, 0, N_SPHERE_C * 4, stream);
    count_k<<<(N_EDGES_C + 255) / 256, 256, 0, stream>>>(receivers, cnt);
    scan_k<<<1, 256, 0, stream>>>(cnt, row_start);
    fill_k<<<(N_EDGES_C + 255) / 256, 256, 0, stream>>>(receivers, row_start, cursor, csr);

    // weight prep
    dim3 tb(16, 16);
    tcast2<<<dim3(16, 16), tb, 0, stream>>>(As_, Ast, 256);
    tcast2<<<dim3(16, 16), tb, 0, stream>>>(Ar,  Art, 256);
    tcast2<<<dim3(16, 16), tb, 0, stream>>>(Bs_, Bst, 256);
    tcast2<<<dim3(16, 16), tb, 0, stream>>>(Br,  Brt, 256);
    tcast2<<<dim3(16, 16), tb, 0, stream>>>(Wn2, Wn2t, 256);
    tcast2<<<dim3(16, 16), tb, 0, stream>>>(Wn1, Bnt, 512);            // top half
    wprod_kernel<<<256, 256, 0, stream>>>(We2, Be, Wft, 256, 0);       // (We2@Be)^T
    wprod_kernel<<<256, 256, 0, stream>>>(We2, Wn1bot, Bnt, 512, 256); // (We2@Wn1b)^T
    bvecprod_kernel<<<1, 256, 0, stream>>>(be1, be2, Be, bfc);
    bvecprod_kernel<<<1, 256, 0, stream>>>(nullptr, be2, Wn1bot, bxv);

    // input casts
    cast_f32_bf16<<<(N_SPATIAL_C * 64 + 255) / 256, 256, 0, stream>>>(
        nodes, nodes_bf, N_SPATIAL_C * 64);
    cast_sphere<<<N_SPHERE_C, 256, 0, stream>>>(nodes, node_in_bf);

    const int GE = N_EDGES_C / 64;              // 2048
    const int GP = (N_SPATIAL_C + 63) / 64;     // 1019
    const int GS = (N_SPHERE_C + 63) / 64;      // 46
    const float* nul = nullptr;

    // P0 = spatial @ As
    mfma_gemm<0, 256, ushort><<<GP, 256, 0, stream>>>(
        nodes_bf, Ast, Pb, N_SPATIAL_C, 256, 256,
        nul, nul, nul, nullptr, nullptr, nul, nullptr, nullptr, nul);

    for (int step = 0; step < 3; ++step) {
        // R = sphere @ W1_r  (sphere = node_in left half, lda=512)
        mfma_gemm<0, 256, float><<<GS, 256, 0, stream>>>(
            node_in_bf, step == 0 ? Art : Brt, Rf, N_SPHERE_C, 512, 256,
            nul, nul, nul, nullptr, nullptr, nul, nullptr, nullptr, nul);

        if (step == 0) {
            fuse0<<<N_EDGES_C / 4, 256, 0, stream>>>(
                edges3, Ae, Pb, senders, Rf, receivers, be1, ge, oe, H);
            // overwrite P with P12 = spatial @ Bs
            mfma_gemm<0, 256, ushort><<<GP, 256, 0, stream>>>(
                nodes_bf, Bst, Pb, N_SPATIAL_C, 256, 256,
                nul, nul, nul, nullptr, nullptr, nul, nullptr, nullptr, nul);
        } else {
            // H = LN(relu(H@Wf + P12[s] + R[rid] + bfc)) * ge + oe   (in place)
            mfma_gemm<2, 256, ushort><<<GE, 256, 0, stream>>>(
                H, Wft, H, N_EDGES_C, 256, 256,
                bfc, ge, oe, Pb, senders, Rf, receivers, nullptr, nul);
        }

        // S = segsum(H) -> node_in right half (stride 512)
        seg_gather<<<N_SPHERE_C, 256, 0, stream>>>(H, row_start, csr,
                                                   node_in_bf + 256, 512);

        // npre = [sphere|S]@Bn + bn1 + cnt*bx ; nH = LN(relu(npre))*gn+on
        mfma_gemm<1, 512, ushort><<<GS, 256, 0, stream>>>(
            node_in_bf, Bnt, nH, N_SPHERE_C, 512, 256,
            bn1, gn, on_, nullptr, nullptr, nul, nullptr, cnt, bxv);

        if (step < 2) {
            // sphere_next = nH@Wn2 + bn2 -> node_in left half (ldc=512)
            mfma_gemm<0, 256, ushort><<<GS, 256, 0, stream>>>(
                nH, Wn2t, node_in_bf, N_SPHERE_C, 256, 512,
                bn2, nul, nul, nullptr, nullptr, nul, nullptr, nullptr, nul);
        } else {
            mfma_gemm<0, 256, float><<<GS, 256, 0, stream>>>(
                nH, Wn2t, (float*)d_out, N_SPHERE_C, 256, 256,
                bn2, nul, nul, nullptr, nullptr, nul, nullptr, nullptr, nul);
        }
    }
}